// Round 2
// 13635.637 us; speedup vs baseline: 1.0510x; 1.0510x over previous
//
#include <hip/hip_runtime.h>
#include <math.h>

#define T_STEPS 4096
#define RES     2048
#define NF      8
#define NR      8
#define K_WG    128      // 128 WGs x 4 waves = 512 waves; each wave owns 4 columns
#define NTHR    256
#define SENTINEL 2.0f    // reachable |x| < 1 strictly; 2.0 is unreachable

// ---------------------------------------------------------------------------
// drive[t][j] = Win[0][j] + sum_f inp[t][f] * Win[1+f][j]
__global__ void k_drive(const float* __restrict__ inp, const float* __restrict__ Win,
                        float* __restrict__ drive) {
    int idx = blockIdx.x * blockDim.x + threadIdx.x;   // [0, T*RES)
    int t = idx >> 11;
    int j = idx & (RES - 1);
    float d = Win[j];
#pragma unroll
    for (int f = 0; f < NF; ++f)
        d += inp[t * NF + f] * Win[(1 + f) * RES + j];
    drive[idx] = d;
}

// ---------------------------------------------------------------------------
// X[0][:] = 0 (initial state, valid); X[1..T][:] = SENTINEL (unwritten)
__global__ void k_init(float* __restrict__ X) {
    int tid = threadIdx.x + blockIdx.x * blockDim.x;
    int stride = blockDim.x * gridDim.x;
    const int total = (T_STEPS + 1) * RES;
    for (int i = tid; i < total; i += stride)
        X[i] = (i < RES) ? 0.f : SENTINEL;
}

// ---------------------------------------------------------------------------
// Persistent dataflow recurrence, WG-cooperative detection.
// Wave w of each WG polls only row-chunk [512w, 512w+512) (8 atomic loads/lane
// instead of 32), deposits it into a double-buffered LDS row, one barrier,
// then all 4 waves compute their columns from LDS. Global poll traffic drops
// 4x (the round-0 bottleneck: 512 waves x 8KB per poll sweep congested the
// LLC and inflated detect latency; FETCH_SIZE showed 12x algorithmic bytes).
//
// Safety of the single barrier + 2-row LDS double buffer:
//  - Barriers stay step-aligned: a wave reaches barrier(t) only after passing
//    barrier(t-1), which is collective -> induction.
//  - buf[t&1] overwrite at step t is safe: passing barrier(t-1) implies every
//    wave finished its step t-2 compute (which is the last reader of buf[t&1]).
//  - Cross-WG progress: dependency graph identical in shape to the verified
//    round-0 kernel; row 0 seeded by k_init; all 128 WGs co-resident.
__global__ __launch_bounds__(NTHR, 1) void k_recur(
        const float* __restrict__ W, const float* __restrict__ drive,
        float* __restrict__ X) {
    __shared__ float xbuf[2][RES];            // 16 KB, double-buffered row cache

    const int tid  = threadIdx.x;
    const int wave = tid >> 6;
    const int lane = tid & 63;
    const int g    = blockIdx.x * 4 + wave;   // [0, 512)
    const int c0   = g * 4;                   // this wave's 4 output columns
    const int cb   = wave * (RES / 4);        // this wave's 512-element poll chunk

    // Load W fragment: Wr[i] = W[i*64+lane][c0 .. c0+4)
    float4 Wr[32];
#pragma unroll
    for (int i = 0; i < 32; ++i)
        Wr[i] = *reinterpret_cast<const float4*>(&W[(size_t)(i * 64 + lane) * RES + c0]);
    // Pin in registers: block the compiler from sinking/rematerializing the
    // loads inside the t-loop (round-1 failure mode: VGPR_Count=84 -> W
    // re-streamed from LLC every step).
#pragma unroll
    for (int i = 0; i < 32; ++i)
        asm volatile("" : "+v"(Wr[i].x), "+v"(Wr[i].y), "+v"(Wr[i].z), "+v"(Wr[i].w));

    // This wave exclusively owns columns c0..c0+3, so the "old x" for the
    // damping term never needs to be re-read from global: carry it in a reg.
    float xprev = 0.f;                        // X[0][:] == 0

    for (int t = 0; t < T_STEPS; ++t) {
        const float* xrow = X + (size_t)t * RES;

        // Independent of x_t: prefetch drive for this wave's columns.
        float dr = 0.f;
        if (lane < 4) dr = drive[(size_t)t * RES + c0 + lane];

        // Poll ONLY this wave's quarter of row t until sentinel-free.
        // Relaxed agent-scope loads bypass L1/L2 (cross-XCD visibility).
        float xv[8];
        for (;;) {
#pragma unroll
            for (int i = 0; i < 8; ++i)
                xv[i] = __hip_atomic_load(&xrow[cb + i * 64 + lane],
                                          __ATOMIC_RELAXED, __HIP_MEMORY_SCOPE_AGENT);
            float m = 0.f;
#pragma unroll
            for (int i = 0; i < 8; ++i)
                m = fmaxf(m, __builtin_fabsf(xv[i]));
            if (__all(m < 1.5f)) break;       // chunk verified across the wave
            __builtin_amdgcn_s_sleep(1);
        }

        // Deposit verified chunk into this step's LDS row buffer.
        float* buf = xbuf[t & 1];
#pragma unroll
        for (int i = 0; i < 8; ++i)
            buf[cb + i * 64 + lane] = xv[i];
        __syncthreads();                      // whole row now valid in LDS

        // z[c0+j] = sum_i x[i*64+lane] * W[i*64+lane][c0+j], partial per lane.
        // LDS reads: addr stride 256B -> 2-way bank aliasing only (free).
        float a0 = 0.f, a1 = 0.f, a2 = 0.f, a3 = 0.f;
#pragma unroll
        for (int i = 0; i < 32; ++i) {
            float xs = buf[i * 64 + lane];
            float4 w = Wr[i];
            a0 = fmaf(xs, w.x, a0);
            a1 = fmaf(xs, w.y, a1);
            a2 = fmaf(xs, w.z, a2);
            a3 = fmaf(xs, w.w, a3);
        }
        // 64-lane butterfly: all lanes end with the 4 full column sums.
#pragma unroll
        for (int off = 32; off >= 1; off >>= 1) {
            a0 += __shfl_xor(a0, off, 64);
            a1 += __shfl_xor(a1, off, 64);
            a2 += __shfl_xor(a2, off, 64);
            a3 += __shfl_xor(a3, off, 64);
        }

        if (lane < 4) {
            float a  = lane == 0 ? a0 : lane == 1 ? a1 : lane == 2 ? a2 : a3;
            float xn = 0.7f * xprev + 0.3f * tanhf(dr + a);
            // Publish: single coalesced 16B (4 lanes x 1 dword), fire-and-forget.
            __hip_atomic_store(&X[(size_t)(t + 1) * RES + c0 + lane], xn,
                               __ATOMIC_RELAXED, __HIP_MEMORY_SCOPE_AGENT);
            xprev = xn;
        }
    }
}

// ---------------------------------------------------------------------------
// Y[t][r] = Wout[0][r] + sum_f inp[t][f]*Wout[1+f][r] + sum_j X[t+1][j]*Wout[9+j][r]
__global__ void k_readout(const float* __restrict__ inp, const float* __restrict__ Wout,
                          const float* __restrict__ X, float* __restrict__ Y) {
    int t   = blockIdx.x;
    int tid = threadIdx.x;
    int r   = tid & (NR - 1);
    int gph = tid >> 3;                    // 32 groups
    const float* x = X + (size_t)(t + 1) * RES;
    float p = 0.f;
#pragma unroll 4
    for (int m = 0; m < RES / 32; ++m) {
        int j = gph * (RES / 32) + m;
        p += x[j] * Wout[(size_t)(1 + NF + j) * NR + r];
    }
    __shared__ float red[NTHR];
    red[tid] = p;
    __syncthreads();
    for (int s = NTHR / 2; s >= NR; s >>= 1) {
        if (tid < s) red[tid] += red[tid + s];
        __syncthreads();
    }
    if (tid < NR) {
        float y = Wout[tid];
#pragma unroll
        for (int f = 0; f < NF; ++f)
            y += inp[t * NF + f] * Wout[(1 + f) * NR + tid];
        Y[t * NR + tid] = y + red[tid];
    }
}

// ---------------------------------------------------------------------------
extern "C" void kernel_launch(void* const* d_in, const int* in_sizes, int n_in,
                              void* d_out, int out_size, void* d_ws, size_t ws_size,
                              hipStream_t stream) {
    const float* inp  = (const float*)d_in[0];   // (T, 8)
    const float* Win  = (const float*)d_in[1];   // (9, 2048)
    const float* W    = (const float*)d_in[2];   // (2048, 2048)
    const float* Wout = (const float*)d_in[3];   // (2057, 8)
    float* Y = (float*)d_out;                    // (T, 8)

    float* drive = (float*)d_ws;                            // 32 MB
    float* X     = drive + (size_t)T_STEPS * RES;           // 32 MB + 8 KB

    k_init<<<2048, NTHR, 0, stream>>>(X);
    k_drive<<<(T_STEPS * RES) / NTHR, NTHR, 0, stream>>>(inp, Win, drive);
    k_recur<<<K_WG, NTHR, 0, stream>>>(W, drive, X);
    k_readout<<<T_STEPS, NTHR, 0, stream>>>(inp, Wout, X, Y);
}

// Round 3
// 11380.903 us; speedup vs baseline: 1.2592x; 1.1981x over previous
//
#include <hip/hip_runtime.h>
#include <math.h>

#define T_STEPS 4096
#define RES     2048
#define NF      8
#define NR      8
#define K_WG    128      // 128 WGs x 4 waves = 512 waves; each wave owns 4 columns
#define NTHR    256
#define SENTINEL 2.0f    // reachable |x| < 1 strictly; 2.0 is unreachable
#define VALID_MASK 0x7fffffffu
#define VALID_LIM  0x3f800000u   // abs-bits < 1.0f  <=> valid; sentinel 2.0f fails

typedef unsigned long long u64;
typedef unsigned int       u32;

// ---------------------------------------------------------------------------
// drive[t][j] = Win[0][j] + sum_f inp[t][f] * Win[1+f][j]
__global__ void k_drive(const float* __restrict__ inp, const float* __restrict__ Win,
                        float* __restrict__ drive) {
    int idx = blockIdx.x * blockDim.x + threadIdx.x;   // [0, T*RES)
    int t = idx >> 11;
    int j = idx & (RES - 1);
    float d = Win[j];
#pragma unroll
    for (int f = 0; f < NF; ++f)
        d += inp[t * NF + f] * Win[(1 + f) * RES + j];
    drive[idx] = d;
}

// ---------------------------------------------------------------------------
// X[0][:] = 0 (initial state, valid); X[1..T][:] = SENTINEL (unwritten)
__global__ void k_init(float* __restrict__ X) {
    int tid = threadIdx.x + blockIdx.x * blockDim.x;
    int stride = blockDim.x * gridDim.x;
    const int total = (T_STEPS + 1) * RES;
    for (int i = tid; i < total; i += stride)
        X[i] = (i < RES) ? 0.f : SENTINEL;
}

// ---------------------------------------------------------------------------
// Persistent dataflow recurrence, WG-cooperative detection.
// Round-2 evidence: poll BYTES are not the constraint (4x cut -> -5% dur;
// beyond-L2 FETCH 0.47GB << one-sweep-per-step minimum 4.3GB, so polls are
// cache-absorbed). The binding constraint is the per-step detect critical
// path x max-over-512-waves tail. This round minimizes the poll ITERATION:
//  - 4x 64-bit atomic loads per lane (was 8x 32-bit)
//  - integer sentinel check (abs-bits < 0x3f800000), no float fmax chain
//  - no s_sleep in steady state (spin hard; throttle only after 64 sweeps
//    to protect the cold-start ramp)
//  - drive[] prefetched one step ahead (HBM latency off the critical path)
//
// Safety of the single barrier + 2-row LDS double buffer:
//  - Barriers stay step-aligned: a wave reaches barrier(t) only after passing
//    barrier(t-1), which is collective -> induction.
//  - buf[t&1] overwrite at step t is safe: passing barrier(t-1) implies every
//    wave finished its step t-2 compute (the last reader of buf[t&1]).
//  - Cross-WG progress: row 0 seeded by k_init; all 128 WGs co-resident.
__global__ __launch_bounds__(NTHR, 1) void k_recur(
        const float* __restrict__ W, const float* __restrict__ drive,
        float* __restrict__ X) {
    __shared__ float xbuf[2][RES];            // 16 KB, double-buffered row cache

    const int tid  = threadIdx.x;
    const int wave = tid >> 6;
    const int lane = tid & 63;
    const int g    = blockIdx.x * 4 + wave;   // [0, 512)
    const int c0   = g * 4;                   // this wave's 4 output columns
    const int cb   = wave * (RES / 4);        // this wave's 512-float poll chunk

    // Load W fragment: Wr[i] = W[i*64+lane][c0 .. c0+4)
    float4 Wr[32];
#pragma unroll
    for (int i = 0; i < 32; ++i)
        Wr[i] = *reinterpret_cast<const float4*>(&W[(size_t)(i * 64 + lane) * RES + c0]);
    // Pin: block the compiler from sinking/rematerializing the loads inside
    // the t-loop (prior failure mode: W re-streamed from LLC every step).
#pragma unroll
    for (int i = 0; i < 32; ++i)
        asm volatile("" : "+v"(Wr[i].x), "+v"(Wr[i].y), "+v"(Wr[i].z), "+v"(Wr[i].w));

    // This wave exclusively owns columns c0..c0+3: carry old x in a register.
    float xprev = 0.f;                        // X[0][:] == 0

    // drive prefetch pipeline: dr holds this step's value.
    float dr = 0.f;
    if (lane < 4) dr = drive[c0 + lane];      // t = 0

    for (int t = 0; t < T_STEPS; ++t) {
        // Poll ONLY this wave's quarter of row t until sentinel-free.
        // 64-bit relaxed agent-scope loads; validity via integer abs compare
        // (valid |x| < 1.0 strictly; sentinel 2.0f = 0x40000000 fails).
        const u64* xrow64 = reinterpret_cast<const u64*>(X + (size_t)t * RES) + (cb >> 1);
        u64 xv[4];
        int spins = 0;
        for (;;) {
#pragma unroll
            for (int i = 0; i < 4; ++i)
                xv[i] = __hip_atomic_load(&xrow64[i * 64 + lane],
                                          __ATOMIC_RELAXED, __HIP_MEMORY_SCOPE_AGENT);
            u32 m = 0;
#pragma unroll
            for (int i = 0; i < 4; ++i) {
                u32 lo = (u32)(xv[i])       & VALID_MASK;
                u32 hi = (u32)(xv[i] >> 32) & VALID_MASK;
                u32 mx = lo > hi ? lo : hi;
                m = m > mx ? m : mx;
            }
            if (__all(m < VALID_LIM)) break;  // chunk verified across the wave
            if (++spins > 64) __builtin_amdgcn_s_sleep(1);   // ramp throttle only
        }

        // Deposit verified chunk into this step's LDS row buffer (8B stores).
        u64* b64 = reinterpret_cast<u64*>(xbuf[t & 1]) + (cb >> 1);
#pragma unroll
        for (int i = 0; i < 4; ++i)
            b64[i * 64 + lane] = xv[i];
        __syncthreads();                      // whole row now valid in LDS

        // Prefetch next step's drive (consumed ~a full step later).
        float dr_n = 0.f;
        if (lane < 4 && t + 1 < T_STEPS)
            dr_n = drive[(size_t)(t + 1) * RES + c0 + lane];

        // z[c0+j] = sum_i x[i*64+lane] * W[i*64+lane][c0+j], partial per lane.
        // LDS reads: stride 256B -> 2-way bank aliasing only (free).
        const float* buf = xbuf[t & 1];
        float a0 = 0.f, a1 = 0.f, a2 = 0.f, a3 = 0.f;
#pragma unroll
        for (int i = 0; i < 32; ++i) {
            float xs = buf[i * 64 + lane];
            float4 w = Wr[i];
            a0 = fmaf(xs, w.x, a0);
            a1 = fmaf(xs, w.y, a1);
            a2 = fmaf(xs, w.z, a2);
            a3 = fmaf(xs, w.w, a3);
        }
        // 64-lane butterfly: all lanes end with the 4 full column sums.
#pragma unroll
        for (int off = 32; off >= 1; off >>= 1) {
            a0 += __shfl_xor(a0, off, 64);
            a1 += __shfl_xor(a1, off, 64);
            a2 += __shfl_xor(a2, off, 64);
            a3 += __shfl_xor(a3, off, 64);
        }

        if (lane < 4) {
            float a  = lane == 0 ? a0 : lane == 1 ? a1 : lane == 2 ? a2 : a3;
            float xn = 0.7f * xprev + 0.3f * tanhf(dr + a);
            // Publish: single coalesced 16B (4 lanes x 1 dword), fire-and-forget.
            __hip_atomic_store(&X[(size_t)(t + 1) * RES + c0 + lane], xn,
                               __ATOMIC_RELAXED, __HIP_MEMORY_SCOPE_AGENT);
            xprev = xn;
        }
        dr = dr_n;
    }
}

// ---------------------------------------------------------------------------
// Y[t][r] = Wout[0][r] + sum_f inp[t][f]*Wout[1+f][r] + sum_j X[t+1][j]*Wout[9+j][r]
__global__ void k_readout(const float* __restrict__ inp, const float* __restrict__ Wout,
                          const float* __restrict__ X, float* __restrict__ Y) {
    int t   = blockIdx.x;
    int tid = threadIdx.x;
    int r   = tid & (NR - 1);
    int gph = tid >> 3;                    // 32 groups
    const float* x = X + (size_t)(t + 1) * RES;
    float p = 0.f;
#pragma unroll 4
    for (int m = 0; m < RES / 32; ++m) {
        int j = gph * (RES / 32) + m;
        p += x[j] * Wout[(size_t)(1 + NF + j) * NR + r];
    }
    __shared__ float red[NTHR];
    red[tid] = p;
    __syncthreads();
    for (int s = NTHR / 2; s >= NR; s >>= 1) {
        if (tid < s) red[tid] += red[tid + s];
        __syncthreads();
    }
    if (tid < NR) {
        float y = Wout[tid];
#pragma unroll
        for (int f = 0; f < NF; ++f)
            y += inp[t * NF + f] * Wout[(1 + f) * NR + tid];
        Y[t * NR + tid] = y + red[tid];
    }
}

// ---------------------------------------------------------------------------
extern "C" void kernel_launch(void* const* d_in, const int* in_sizes, int n_in,
                              void* d_out, int out_size, void* d_ws, size_t ws_size,
                              hipStream_t stream) {
    const float* inp  = (const float*)d_in[0];   // (T, 8)
    const float* Win  = (const float*)d_in[1];   // (9, 2048)
    const float* W    = (const float*)d_in[2];   // (2048, 2048)
    const float* Wout = (const float*)d_in[3];   // (2057, 8)
    float* Y = (float*)d_out;                    // (T, 8)

    float* drive = (float*)d_ws;                            // 32 MB
    float* X     = drive + (size_t)T_STEPS * RES;           // 32 MB + 8 KB

    k_init<<<2048, NTHR, 0, stream>>>(X);
    k_drive<<<(T_STEPS * RES) / NTHR, NTHR, 0, stream>>>(inp, Win, drive);
    k_recur<<<K_WG, NTHR, 0, stream>>>(W, drive, X);
    k_readout<<<T_STEPS, NTHR, 0, stream>>>(inp, Wout, X, Y);
}

// Round 4
// 7928.046 us; speedup vs baseline: 1.8077x; 1.4355x over previous
//
#include <hip/hip_runtime.h>
#include <math.h>

#define T_STEPS 4096
#define RES     2048
#define NF      8
#define NR      8
#define K_WG    128      // 128 WGs x 4 waves = 512 waves; each wave owns 4 columns
#define NTHR    256
#define SENTINEL 2.0f    // reachable |x| < 1 strictly; 2.0 is unreachable
#define VALID_MASK 0x7fffffffu
#define VALID_LIM  0x3f800000u   // abs-bits < 1.0f  <=> valid; sentinel 2.0f fails

typedef unsigned long long u64;
typedef unsigned int       u32;

// ---------------------------------------------------------------------------
// drive[t][j] = Win[0][j] + sum_f inp[t][f] * Win[1+f][j]
__global__ void k_drive(const float* __restrict__ inp, const float* __restrict__ Win,
                        float* __restrict__ drive) {
    int idx = blockIdx.x * blockDim.x + threadIdx.x;   // [0, T*RES)
    int t = idx >> 11;
    int j = idx & (RES - 1);
    float d = Win[j];
#pragma unroll
    for (int f = 0; f < NF; ++f)
        d += inp[t * NF + f] * Win[(1 + f) * RES + j];
    drive[idx] = d;
}

// ---------------------------------------------------------------------------
// X[0][:] = 0 (initial state, valid); X[1..T][:] = SENTINEL (unwritten)
__global__ void k_init(float* __restrict__ X) {
    int tid = threadIdx.x + blockIdx.x * blockDim.x;
    int stride = blockDim.x * gridDim.x;
    const int total = (T_STEPS + 1) * RES;
    for (int i = tid; i < total; i += stride)
        X[i] = (i < RES) ? 0.f : SENTINEL;
}

// ---------------------------------------------------------------------------
// Persistent dataflow recurrence, WG-cooperative detection.
// Round-3 evidence: poll-iteration cost was real (-17%); remaining per-step
// 2.77us is the serial chain {publish drain -> LLC visibility -> detect ->
// deposit+barrier -> FMA -> 24-shfl butterfly -> libm tanh -> publish} x
// max-over-512-waves tail. This round shortens the post-detect serial path:
//  - cross-step poll pipelining: row t+1's first sweep issues BEFORE the
//    compute block, hiding its ~250ns LLC latency under FMA/reduce/tanh.
//    Stale pre-publish reads only cause one retry (per-location coherence:
//    our own later store is seen by the retry's reload).
//  - 7-shuffle reduce (was 24): 2 select+xor levels collapse 4 accumulators
//    to one scalar per lane for col c0+(lane&3), then 5 butterfly levels.
//  - fast tanh: 1 - 2*rcp(e+1), e = __expf(2s); exact saturation at +-inf.
//
// Safety of the single barrier + 2-row LDS double buffer: unchanged from
// round 2/3 (collective barrier induction; buf[t&1] last read at step t-2).
__global__ __launch_bounds__(NTHR, 1) void k_recur(
        const float* __restrict__ W, const float* __restrict__ drive,
        float* __restrict__ X) {
    __shared__ float xbuf[2][RES];            // 16 KB, double-buffered row cache

    const int tid  = threadIdx.x;
    const int wave = tid >> 6;
    const int lane = tid & 63;
    const int g    = blockIdx.x * 4 + wave;   // [0, 512)
    const int c0   = g * 4;                   // this wave's 4 output columns
    const int cb   = wave * (RES / 4);        // this wave's 512-float poll chunk
    const int cb2  = cb >> 1;                 // u64 index of chunk base

    // Load W fragment: Wr[i] = W[i*64+lane][c0 .. c0+4)
    float4 Wr[32];
#pragma unroll
    for (int i = 0; i < 32; ++i)
        Wr[i] = *reinterpret_cast<const float4*>(&W[(size_t)(i * 64 + lane) * RES + c0]);
    // Pin: block the compiler from sinking/rematerializing the loads inside
    // the t-loop (prior failure mode: W re-streamed from LLC every step).
#pragma unroll
    for (int i = 0; i < 32; ++i)
        asm volatile("" : "+v"(Wr[i].x), "+v"(Wr[i].y), "+v"(Wr[i].z), "+v"(Wr[i].w));

    // This wave exclusively owns columns c0..c0+3: carry old x in a register.
    float xprev = 0.f;                        // X[0][:] == 0

    // drive prefetch pipeline: dr holds this step's value.
    float dr = 0.f;
    if (lane < 4) dr = drive[c0 + lane];      // t = 0

    // Pre-issue the first poll sweep for row 0 (pipeline prologue).
    u64 xv[4];
    {
        const u64* r0 = reinterpret_cast<const u64*>(X) + cb2;
#pragma unroll
        for (int i = 0; i < 4; ++i)
            xv[i] = __hip_atomic_load(&r0[i * 64 + lane],
                                      __ATOMIC_RELAXED, __HIP_MEMORY_SCOPE_AGENT);
    }

    for (int t = 0; t < T_STEPS; ++t) {
        const u64* xrow64 = reinterpret_cast<const u64*>(X + (size_t)t * RES) + cb2;

        // Detect: first eval consumes the pre-issued sweep; retries reload.
        int spins = 0;
        for (;;) {
            u32 m = 0;
#pragma unroll
            for (int i = 0; i < 4; ++i) {
                u32 lo = (u32)(xv[i])       & VALID_MASK;
                u32 hi = (u32)(xv[i] >> 32) & VALID_MASK;
                u32 mx = lo > hi ? lo : hi;
                m = m > mx ? m : mx;
            }
            if (__all(m < VALID_LIM)) break;  // chunk verified across the wave
            if (++spins > 64) __builtin_amdgcn_s_sleep(1);   // ramp throttle only
#pragma unroll
            for (int i = 0; i < 4; ++i)
                xv[i] = __hip_atomic_load(&xrow64[i * 64 + lane],
                                          __ATOMIC_RELAXED, __HIP_MEMORY_SCOPE_AGENT);
        }

        // Deposit verified chunk into this step's LDS row buffer (8B stores).
        u64* b64 = reinterpret_cast<u64*>(xbuf[t & 1]) + cb2;
#pragma unroll
        for (int i = 0; i < 4; ++i)
            b64[i * 64 + lane] = xv[i];
        __syncthreads();                      // whole row now valid in LDS

        // Pre-issue next row's first sweep: LLC latency hides under compute.
        {
            const u64* nrow64 = reinterpret_cast<const u64*>(
                                    X + (size_t)(t + 1) * RES) + cb2;
#pragma unroll
            for (int i = 0; i < 4; ++i)
                xv[i] = __hip_atomic_load(&nrow64[i * 64 + lane],
                                          __ATOMIC_RELAXED, __HIP_MEMORY_SCOPE_AGENT);
        }

        // Prefetch next step's drive (consumed ~a full step later).
        float dr_n = 0.f;
        if (lane < 4 && t + 1 < T_STEPS)
            dr_n = drive[(size_t)(t + 1) * RES + c0 + lane];

        // z[c0+j] = sum_i x[i*64+lane] * W[i*64+lane][c0+j], partial per lane.
        // LDS reads: stride 256B -> 2-way bank aliasing only (free).
        const float* buf = xbuf[t & 1];
        float a0 = 0.f, a1 = 0.f, a2 = 0.f, a3 = 0.f;
#pragma unroll
        for (int i = 0; i < 32; ++i) {
            float xs = buf[i * 64 + lane];
            float4 w = Wr[i];
            a0 = fmaf(xs, w.x, a0);
            a1 = fmaf(xs, w.y, a1);
            a2 = fmaf(xs, w.z, a2);
            a3 = fmaf(xs, w.w, a3);
        }

        // 7-shuffle reduce. After xor1/xor2 with selection, lane l holds the
        // quad-partial for column c0+(l&3); 4 more levels finish the 16 quads.
        const bool b0 = (lane & 1) != 0;
        const bool b1 = (lane & 2) != 0;
        float u  = b0 ? a1 : a0;
        float v  = b0 ? a0 : a1;
        u += __shfl_xor(v, 1, 64);
        float w2 = b0 ? a3 : a2;
        float z2 = b0 ? a2 : a3;
        w2 += __shfl_xor(z2, 1, 64);
        float p  = b1 ? w2 : u;
        float q  = b1 ? u : w2;
        p += __shfl_xor(q, 2, 64);
        p += __shfl_xor(p, 4, 64);
        p += __shfl_xor(p, 8, 64);
        p += __shfl_xor(p, 16, 64);
        p += __shfl_xor(p, 32, 64);

        if (lane < 4) {                       // lane l holds column c0+l
            float s  = dr + p;
            float e  = __expf(2.0f * s);      // v_exp_f32 fast path
            float th = 1.0f - 2.0f * __builtin_amdgcn_rcpf(e + 1.0f);
            float xn = 0.7f * xprev + 0.3f * th;
            // Publish: single coalesced 16B (4 lanes x 1 dword), fire-and-forget.
            __hip_atomic_store(&X[(size_t)(t + 1) * RES + c0 + lane], xn,
                               __ATOMIC_RELAXED, __HIP_MEMORY_SCOPE_AGENT);
            xprev = xn;
        }
        dr = dr_n;
    }
}

// ---------------------------------------------------------------------------
// Y[t][r] = Wout[0][r] + sum_f inp[t][f]*Wout[1+f][r] + sum_j X[t+1][j]*Wout[9+j][r]
__global__ void k_readout(const float* __restrict__ inp, const float* __restrict__ Wout,
                          const float* __restrict__ X, float* __restrict__ Y) {
    int t   = blockIdx.x;
    int tid = threadIdx.x;
    int r   = tid & (NR - 1);
    int gph = tid >> 3;                    // 32 groups
    const float* x = X + (size_t)(t + 1) * RES;
    float p = 0.f;
#pragma unroll 4
    for (int m = 0; m < RES / 32; ++m) {
        int j = gph * (RES / 32) + m;
        p += x[j] * Wout[(size_t)(1 + NF + j) * NR + r];
    }
    __shared__ float red[NTHR];
    red[tid] = p;
    __syncthreads();
    for (int s = NTHR / 2; s >= NR; s >>= 1) {
        if (tid < s) red[tid] += red[tid + s];
        __syncthreads();
    }
    if (tid < NR) {
        float y = Wout[tid];
#pragma unroll
        for (int f = 0; f < NF; ++f)
            y += inp[t * NF + f] * Wout[(1 + f) * NR + tid];
        Y[t * NR + tid] = y + red[tid];
    }
}

// ---------------------------------------------------------------------------
extern "C" void kernel_launch(void* const* d_in, const int* in_sizes, int n_in,
                              void* d_out, int out_size, void* d_ws, size_t ws_size,
                              hipStream_t stream) {
    const float* inp  = (const float*)d_in[0];   // (T, 8)
    const float* Win  = (const float*)d_in[1];   // (9, 2048)
    const float* W    = (const float*)d_in[2];   // (2048, 2048)
    const float* Wout = (const float*)d_in[3];   // (2057, 8)
    float* Y = (float*)d_out;                    // (T, 8)

    float* drive = (float*)d_ws;                            // 32 MB
    float* X     = drive + (size_t)T_STEPS * RES;           // 32 MB + 8 KB

    k_init<<<2048, NTHR, 0, stream>>>(X);
    k_drive<<<(T_STEPS * RES) / NTHR, NTHR, 0, stream>>>(inp, Win, drive);
    k_recur<<<K_WG, NTHR, 0, stream>>>(W, drive, X);
    k_readout<<<T_STEPS, NTHR, 0, stream>>>(inp, Wout, X, Y);
}

// Round 5
// 7885.172 us; speedup vs baseline: 1.8175x; 1.0054x over previous
//
#include <hip/hip_runtime.h>
#include <math.h>

#define T_STEPS 4096
#define RES     2048
#define NF      8
#define NR      8
#define K_WG    128      // 128 WGs x 4 waves = 512 waves; each wave owns 4 columns
#define NTHR    256
#define SENTINEL 2.0f    // reachable |x| < 1 strictly; 2.0 is unreachable
#define VALID_MASK 0x7fffffffu
#define VALID_LIM  0x3f800000u   // abs-bits < 1.0f  <=> valid; sentinel 2.0f fails
#define DBLK 32          // drive block: steps per batched drive load

typedef unsigned long long u64;
typedef unsigned int       u32;

// ---------------------------------------------------------------------------
// drive[t][j] = Win[0][j] + sum_f inp[t][f] * Win[1+f][j]
__global__ void k_drive(const float* __restrict__ inp, const float* __restrict__ Win,
                        float* __restrict__ drive) {
    int idx = blockIdx.x * blockDim.x + threadIdx.x;   // [0, T*RES)
    int t = idx >> 11;
    int j = idx & (RES - 1);
    float d = Win[j];
#pragma unroll
    for (int f = 0; f < NF; ++f)
        d += inp[t * NF + f] * Win[(1 + f) * RES + j];
    drive[idx] = d;
}

// ---------------------------------------------------------------------------
// X[0][:] = 0 (initial state, valid); X[1..T][:] = SENTINEL (unwritten)
__global__ void k_init(float* __restrict__ X) {
    int tid = threadIdx.x + blockIdx.x * blockDim.x;
    int stride = blockDim.x * gridDim.x;
    const int total = (T_STEPS + 1) * RES;
    for (int i = tid; i < total; i += stride)
        X[i] = (i < RES) ? 0.f : SENTINEL;
}

// ---------------------------------------------------------------------------
// Persistent dataflow recurrence, WG-cooperative detection.
// Round-4 landed 1.91us/step. Remaining detect cost analysis: vmcnt retires
// IN ORDER, so the per-step drive[] prefetch (HBM, ~900ns) -- older than any
// detect-retry load -- poisoned every retry's s_waitcnt vmcnt(0). This round
// removes ALL per-step VMEM except {poll loads, publish store}:
//  - drive is read in 32-step blocks: ONE u64 load per lane per 32 steps
//    (lane L covers step L>>1, col pair (L&1)*2; 64B lines fully used across
//    the WG). Per-step distribution to lanes 0-3 via two __shfl (DS ops --
//    lgkmcnt, can't block vmcnt waits).
//  - block prefetched one block ahead (32 steps of slack vs ~900ns HBM).
//
// Other structure unchanged from round 4 (cross-step poll pipelining,
// 7-shuffle reduce, fast tanh, int sentinel check, quarter-chunk polling,
// LDS double buffer + single collective barrier per step).
__global__ __launch_bounds__(NTHR, 1) void k_recur(
        const float* __restrict__ W, const float* __restrict__ drive,
        float* __restrict__ X) {
    __shared__ float xbuf[2][RES];            // 16 KB, double-buffered row cache

    const int tid  = threadIdx.x;
    const int wave = tid >> 6;
    const int lane = tid & 63;
    const int g    = blockIdx.x * 4 + wave;   // [0, 512)
    const int c0   = g * 4;                   // this wave's 4 output columns
    const int cb   = wave * (RES / 4);        // this wave's 512-float poll chunk
    const int cb2  = cb >> 1;                 // u64 index of chunk base

    // Load W fragment: Wr[i] = W[i*64+lane][c0 .. c0+4)
    float4 Wr[32];
#pragma unroll
    for (int i = 0; i < 32; ++i)
        Wr[i] = *reinterpret_cast<const float4*>(&W[(size_t)(i * 64 + lane) * RES + c0]);
    // Pin: block the compiler from sinking/rematerializing the loads inside
    // the t-loop (prior failure mode: W re-streamed from LLC every step).
#pragma unroll
    for (int i = 0; i < 32; ++i)
        asm volatile("" : "+v"(Wr[i].x), "+v"(Wr[i].y), "+v"(Wr[i].z), "+v"(Wr[i].w));

    // This wave exclusively owns columns c0..c0+3: carry old x in a register.
    float xprev = 0.f;                        // X[0][:] == 0

    // Batched drive: lane L's u64 covers block-step s=L>>1, cols c0+(L&1)*2+{0,1}.
    // 8B-aligned: RES even, c0 % 4 == 0.
    auto drv_addr = [&](int tb) {
        return reinterpret_cast<const u64*>(
                   &drive[(size_t)(tb + (lane >> 1)) * RES + c0 + (lane & 1) * 2]);
    };
    u64 dcur = *drv_addr(0);                  // block [0,32)
    u64 dnxt = *drv_addr(DBLK);               // block [32,64)

    // Pre-issue the first poll sweep for row 0 (pipeline prologue).
    u64 xv[4];
    {
        const u64* r0 = reinterpret_cast<const u64*>(X) + cb2;
#pragma unroll
        for (int i = 0; i < 4; ++i)
            xv[i] = __hip_atomic_load(&r0[i * 64 + lane],
                                      __ATOMIC_RELAXED, __HIP_MEMORY_SCOPE_AGENT);
    }

    for (int t = 0; t < T_STEPS; ++t) {
        const u64* xrow64 = reinterpret_cast<const u64*>(X + (size_t)t * RES) + cb2;

        // Detect: first eval consumes the pre-issued sweep; retries reload.
        // Steady-state VMEM queue here = {sweeps (older), publish store}:
        // no long-latency HBM op can sit under the retry's vmcnt wait.
        int spins = 0;
        for (;;) {
            u32 m = 0;
#pragma unroll
            for (int i = 0; i < 4; ++i) {
                u32 lo = (u32)(xv[i])       & VALID_MASK;
                u32 hi = (u32)(xv[i] >> 32) & VALID_MASK;
                u32 mx = lo > hi ? lo : hi;
                m = m > mx ? m : mx;
            }
            if (__all(m < VALID_LIM)) break;  // chunk verified across the wave
            if (++spins > 64) __builtin_amdgcn_s_sleep(1);   // ramp throttle only
#pragma unroll
            for (int i = 0; i < 4; ++i)
                xv[i] = __hip_atomic_load(&xrow64[i * 64 + lane],
                                          __ATOMIC_RELAXED, __HIP_MEMORY_SCOPE_AGENT);
        }

        // Deposit verified chunk into this step's LDS row buffer (8B stores).
        u64* b64 = reinterpret_cast<u64*>(xbuf[t & 1]) + cb2;
#pragma unroll
        for (int i = 0; i < 4; ++i)
            b64[i * 64 + lane] = xv[i];
        __syncthreads();                      // whole row now valid in LDS

        // Pre-issue next row's first sweep: LLC latency hides under compute.
        {
            const u64* nrow64 = reinterpret_cast<const u64*>(
                                    X + (size_t)(t + 1) * RES) + cb2;
#pragma unroll
            for (int i = 0; i < 4; ++i)
                xv[i] = __hip_atomic_load(&nrow64[i * 64 + lane],
                                          __ATOMIC_RELAXED, __HIP_MEMORY_SCOPE_AGENT);
        }

        // Extract this step's drive for lanes 0-3 from the block registers.
        // Two DS shuffles (lgkmcnt) -- invisible to detect-retry vmcnt waits.
        const int s = t & (DBLK - 1);
        float dr;
        {
            float lo = __uint_as_float((u32)dcur);
            float hi = __uint_as_float((u32)(dcur >> 32));
            int   src = 2 * s + ((lane & 3) >> 1);       // clamped for lanes >= 4
            float v0 = __shfl(lo, src, 64);
            float v1 = __shfl(hi, src, 64);
            dr = (lane & 1) ? v1 : v0;                   // lanes 0-3: cols c0+0..3
        }
        // Block boundary: rotate prefetched block in, issue next (1/32 steps).
        if (s == DBLK - 1 && t + 1 < T_STEPS) {
            dcur = dnxt;                                 // data long since landed
            int tb2 = t + 1 + DBLK;
            if (tb2 < T_STEPS) dnxt = *drv_addr(tb2);
        }

        // z[c0+j] = sum_i x[i*64+lane] * W[i*64+lane][c0+j], partial per lane.
        // LDS reads: stride 256B -> 2-way bank aliasing only (free).
        const float* buf = xbuf[t & 1];
        float a0 = 0.f, a1 = 0.f, a2 = 0.f, a3 = 0.f;
#pragma unroll
        for (int i = 0; i < 32; ++i) {
            float xs = buf[i * 64 + lane];
            float4 w = Wr[i];
            a0 = fmaf(xs, w.x, a0);
            a1 = fmaf(xs, w.y, a1);
            a2 = fmaf(xs, w.z, a2);
            a3 = fmaf(xs, w.w, a3);
        }

        // 7-shuffle reduce. After xor1/xor2 with selection, lane l holds the
        // quad-partial for column c0+(l&3); 5 more levels finish the 16 quads.
        const bool b0 = (lane & 1) != 0;
        const bool b1 = (lane & 2) != 0;
        float u  = b0 ? a1 : a0;
        float v  = b0 ? a0 : a1;
        u += __shfl_xor(v, 1, 64);
        float w2 = b0 ? a3 : a2;
        float z2 = b0 ? a2 : a3;
        w2 += __shfl_xor(z2, 1, 64);
        float p  = b1 ? w2 : u;
        float q  = b1 ? u : w2;
        p += __shfl_xor(q, 2, 64);
        p += __shfl_xor(p, 4, 64);
        p += __shfl_xor(p, 8, 64);
        p += __shfl_xor(p, 16, 64);
        p += __shfl_xor(p, 32, 64);

        if (lane < 4) {                       // lane l holds column c0+l
            float ss = dr + p;
            float e  = __expf(2.0f * ss);     // v_exp_f32 fast path
            float th = 1.0f - 2.0f * __builtin_amdgcn_rcpf(e + 1.0f);
            float xn = 0.7f * xprev + 0.3f * th;
            // Publish: single coalesced 16B (4 lanes x 1 dword), fire-and-forget.
            __hip_atomic_store(&X[(size_t)(t + 1) * RES + c0 + lane], xn,
                               __ATOMIC_RELAXED, __HIP_MEMORY_SCOPE_AGENT);
            xprev = xn;
        }
    }
}

// ---------------------------------------------------------------------------
// Y[t][r] = Wout[0][r] + sum_f inp[t][f]*Wout[1+f][r] + sum_j X[t+1][j]*Wout[9+j][r]
__global__ void k_readout(const float* __restrict__ inp, const float* __restrict__ Wout,
                          const float* __restrict__ X, float* __restrict__ Y) {
    int t   = blockIdx.x;
    int tid = threadIdx.x;
    int r   = tid & (NR - 1);
    int gph = tid >> 3;                    // 32 groups
    const float* x = X + (size_t)(t + 1) * RES;
    float p = 0.f;
#pragma unroll 4
    for (int m = 0; m < RES / 32; ++m) {
        int j = gph * (RES / 32) + m;
        p += x[j] * Wout[(size_t)(1 + NF + j) * NR + r];
    }
    __shared__ float red[NTHR];
    red[tid] = p;
    __syncthreads();
    for (int s = NTHR / 2; s >= NR; s >>= 1) {
        if (tid < s) red[tid] += red[tid + s];
        __syncthreads();
    }
    if (tid < NR) {
        float y = Wout[tid];
#pragma unroll
        for (int f = 0; f < NF; ++f)
            y += inp[t * NF + f] * Wout[(1 + f) * NR + tid];
        Y[t * NR + tid] = y + red[tid];
    }
}

// ---------------------------------------------------------------------------
extern "C" void kernel_launch(void* const* d_in, const int* in_sizes, int n_in,
                              void* d_out, int out_size, void* d_ws, size_t ws_size,
                              hipStream_t stream) {
    const float* inp  = (const float*)d_in[0];   // (T, 8)
    const float* Win  = (const float*)d_in[1];   // (9, 2048)
    const float* W    = (const float*)d_in[2];   // (2048, 2048)
    const float* Wout = (const float*)d_in[3];   // (2057, 8)
    float* Y = (float*)d_out;                    // (T, 8)

    float* drive = (float*)d_ws;                            // 32 MB
    float* X     = drive + (size_t)T_STEPS * RES;           // 32 MB + 8 KB

    k_init<<<2048, NTHR, 0, stream>>>(X);
    k_drive<<<(T_STEPS * RES) / NTHR, NTHR, 0, stream>>>(inp, Win, drive);
    k_recur<<<K_WG, NTHR, 0, stream>>>(W, drive, X);
    k_readout<<<T_STEPS, NTHR, 0, stream>>>(inp, Wout, X, Y);
}

// Round 6
// 6398.005 us; speedup vs baseline: 2.2399x; 1.2324x over previous
//
#include <hip/hip_runtime.h>
#include <math.h>

#define T_STEPS 4096
#define RES     2048
#define NF      8
#define NR      8
#define K_WG    512      // 512 single-wave WGs; each wave owns 4 columns
#define WTHR    64       // k_recur block = 1 wave
#define NTHR    256      // helper-kernel block size
#define SENTINEL 2.0f    // reachable |x| < 1 strictly; 2.0 is unreachable
#define VALID_MASK 0x7fffffffu
#define VALID_LIM  0x3f800000u   // abs-bits < 1.0f  <=> valid; sentinel 2.0f fails
#define DBLK 32          // drive block: steps per batched drive load

typedef unsigned long long u64;
typedef unsigned int       u32;

// ---------------------------------------------------------------------------
// drive[t][j] = Win[0][j] + sum_f inp[t][f] * Win[1+f][j]
__global__ void k_drive(const float* __restrict__ inp, const float* __restrict__ Win,
                        float* __restrict__ drive) {
    int idx = blockIdx.x * blockDim.x + threadIdx.x;   // [0, T*RES)
    int t = idx >> 11;
    int j = idx & (RES - 1);
    float d = Win[j];
#pragma unroll
    for (int f = 0; f < NF; ++f)
        d += inp[t * NF + f] * Win[(1 + f) * RES + j];
    drive[idx] = d;
}

// ---------------------------------------------------------------------------
// X[0][:] = 0 (initial state, valid); X[1..T][:] = SENTINEL (unwritten)
__global__ void k_init(float* __restrict__ X) {
    int tid = threadIdx.x + blockIdx.x * blockDim.x;
    int stride = blockDim.x * gridDim.x;
    const int total = (T_STEPS + 1) * RES;
    for (int i = tid; i < total; i += stride)
        X[i] = (i < RES) ? 0.f : SENTINEL;
}

// ---------------------------------------------------------------------------
// Persistent dataflow recurrence -- INDEPENDENT single-wave workgroups.
// Round-5 evidence chain: poll bytes cheap (r2), poll iteration real (r3),
// post-detect serial path real (r4), vmcnt poisoning innocent (r5). The
// remaining suspect is the WG-cooperative stage itself (deposit + barrier +
// sibling-detect coupling + LDS round trip), bought in r2 for a byte saving
// now known worthless. This round deletes it:
//  - each wave polls the FULL row privately as 16 u64/lane and keeps it in
//    registers: lane l owns floats {2l+128i, 2l+1+128i | i<16};
//  - W fragment re-indexed to the same ownership, so detect feeds the FMA
//    loop straight from registers: no LDS, no barrier, no sibling skew;
//  - 512 single-wave WGs spread over 256 CUs (2/CU) instead of 128 CUs:
//    halves per-CU poll/LLC contention.
// Poll traffic rises 4x vs r5 -- accepted per r2's measurement.
//
// Correctness structure == round-0 verified kernel: row 0 seeded by k_init,
// sentinel-polling per-location, relaxed agent-scope ops, all WGs resident
// (512 WGs x 1 wave on 256 CUs), forward progress by induction on rows.
__global__ __launch_bounds__(WTHR, 1) void k_recur(
        const float* __restrict__ W, const float* __restrict__ drive,
        float* __restrict__ X) {
    const int lane = threadIdx.x & 63;
    const int g    = blockIdx.x;              // [0, 512)
    const int c0   = g * 4;                   // this wave's 4 output columns

    // W fragment matching register-row ownership:
    // Wr[2i] = W[2*lane+128i][c0..c0+4), Wr[2i+1] = W[2*lane+1+128i][c0..c0+4)
    float4 Wr[32];
#pragma unroll
    for (int i = 0; i < 16; ++i) {
        size_t r0 = (size_t)(2 * lane + 128 * i);
        Wr[2 * i]     = *reinterpret_cast<const float4*>(&W[r0 * RES + c0]);
        Wr[2 * i + 1] = *reinterpret_cast<const float4*>(&W[(r0 + 1) * RES + c0]);
    }
    // Pin: block the compiler from sinking/rematerializing the loads inside
    // the t-loop (prior failure mode: W re-streamed from LLC every step).
#pragma unroll
    for (int i = 0; i < 32; ++i)
        asm volatile("" : "+v"(Wr[i].x), "+v"(Wr[i].y), "+v"(Wr[i].z), "+v"(Wr[i].w));

    // This wave exclusively owns columns c0..c0+3: carry old x in a register.
    float xprev = 0.f;                        // X[0][:] == 0

    // Batched drive: lane L's u64 covers block-step s=L>>1, cols c0+(L&1)*2+{0,1}.
    auto drv_addr = [&](int tb) {
        return reinterpret_cast<const u64*>(
                   &drive[(size_t)(tb + (lane >> 1)) * RES + c0 + (lane & 1) * 2]);
    };
    u64 dcur = *drv_addr(0);                  // block [0,32)
    u64 dnxt = *drv_addr(DBLK);               // block [32,64)

    // Pre-issue the first poll sweep for row 0 (pipeline prologue).
    // Lane l loads u64 indices l + 64i -> floats {2l+128i, 2l+1+128i}.
    u64 xv[16];
    {
        const u64* r0 = reinterpret_cast<const u64*>(X);
#pragma unroll
        for (int i = 0; i < 16; ++i)
            xv[i] = __hip_atomic_load(&r0[i * 64 + lane],
                                      __ATOMIC_RELAXED, __HIP_MEMORY_SCOPE_AGENT);
    }

    for (int t = 0; t < T_STEPS; ++t) {
        const u64* xrow64 = reinterpret_cast<const u64*>(X + (size_t)t * RES);

        // Detect: first eval consumes the pre-issued sweep; retries reload.
        int spins = 0;
        for (;;) {
            u32 m = 0;
#pragma unroll
            for (int i = 0; i < 16; ++i) {
                u32 lo = (u32)(xv[i])       & VALID_MASK;
                u32 hi = (u32)(xv[i] >> 32) & VALID_MASK;
                u32 mx = lo > hi ? lo : hi;
                m = m > mx ? m : mx;
            }
            if (__all(m < VALID_LIM)) break;  // full row verified across the wave
            if (++spins > 64) __builtin_amdgcn_s_sleep(1);   // ramp throttle only
#pragma unroll
            for (int i = 0; i < 16; ++i)
                xv[i] = __hip_atomic_load(&xrow64[i * 64 + lane],
                                          __ATOMIC_RELAXED, __HIP_MEMORY_SCOPE_AGENT);
        }

        // Extract this step's drive for lanes 0-3 from the block registers.
        const int s = t & (DBLK - 1);
        float dr;
        {
            float lo = __uint_as_float((u32)dcur);
            float hi = __uint_as_float((u32)(dcur >> 32));
            int   src = 2 * s + ((lane & 3) >> 1);       // clamped for lanes >= 4
            float v0 = __shfl(lo, src, 64);
            float v1 = __shfl(hi, src, 64);
            dr = (lane & 1) ? v1 : v0;                   // lanes 0-3: cols c0+0..3
        }
        if (s == DBLK - 1 && t + 1 < T_STEPS) {
            dcur = dnxt;                                 // data long since landed
            int tb2 = t + 1 + DBLK;
            if (tb2 < T_STEPS) dnxt = *drv_addr(tb2);
        }

        // z[c0+j] = sum over this lane's 32 owned rows, straight from regs.
        float a0 = 0.f, a1 = 0.f, a2 = 0.f, a3 = 0.f;
#pragma unroll
        for (int i = 0; i < 16; ++i) {
            float xlo = __uint_as_float((u32)xv[i]);
            float xhi = __uint_as_float((u32)(xv[i] >> 32));
            float4 wl = Wr[2 * i];
            float4 wh = Wr[2 * i + 1];
            a0 = fmaf(xlo, wl.x, a0); a0 = fmaf(xhi, wh.x, a0);
            a1 = fmaf(xlo, wl.y, a1); a1 = fmaf(xhi, wh.y, a1);
            a2 = fmaf(xlo, wl.z, a2); a2 = fmaf(xhi, wh.z, a2);
            a3 = fmaf(xlo, wl.w, a3); a3 = fmaf(xhi, wh.w, a3);
        }

        // Pre-issue next row's first sweep: LLC latency hides under the
        // reduce + tanh tail (xv dead now that FMAs consumed it).
        {
            const u64* nrow64 = reinterpret_cast<const u64*>(
                                    X + (size_t)(t + 1) * RES);
#pragma unroll
            for (int i = 0; i < 16; ++i)
                xv[i] = __hip_atomic_load(&nrow64[i * 64 + lane],
                                          __ATOMIC_RELAXED, __HIP_MEMORY_SCOPE_AGENT);
        }

        // 7-shuffle reduce. After xor1/xor2 with selection, lane l holds the
        // quad-partial for column c0+(l&3); 5 more levels finish the 16 quads.
        const bool b0 = (lane & 1) != 0;
        const bool b1 = (lane & 2) != 0;
        float u  = b0 ? a1 : a0;
        float v  = b0 ? a0 : a1;
        u += __shfl_xor(v, 1, 64);
        float w2 = b0 ? a3 : a2;
        float z2 = b0 ? a2 : a3;
        w2 += __shfl_xor(z2, 1, 64);
        float p  = b1 ? w2 : u;
        float q  = b1 ? u : w2;
        p += __shfl_xor(q, 2, 64);
        p += __shfl_xor(p, 4, 64);
        p += __shfl_xor(p, 8, 64);
        p += __shfl_xor(p, 16, 64);
        p += __shfl_xor(p, 32, 64);

        if (lane < 4) {                       // lane l holds column c0+l
            float ss = dr + p;
            float e  = __expf(2.0f * ss);     // v_exp_f32 fast path
            float th = 1.0f - 2.0f * __builtin_amdgcn_rcpf(e + 1.0f);
            float xn = 0.7f * xprev + 0.3f * th;
            // Publish: single coalesced 16B (4 lanes x 1 dword), fire-and-forget.
            __hip_atomic_store(&X[(size_t)(t + 1) * RES + c0 + lane], xn,
                               __ATOMIC_RELAXED, __HIP_MEMORY_SCOPE_AGENT);
            xprev = xn;
        }
    }
}

// ---------------------------------------------------------------------------
// Y[t][r] = Wout[0][r] + sum_f inp[t][f]*Wout[1+f][r] + sum_j X[t+1][j]*Wout[9+j][r]
__global__ void k_readout(const float* __restrict__ inp, const float* __restrict__ Wout,
                          const float* __restrict__ X, float* __restrict__ Y) {
    int t   = blockIdx.x;
    int tid = threadIdx.x;
    int r   = tid & (NR - 1);
    int gph = tid >> 3;                    // 32 groups
    const float* x = X + (size_t)(t + 1) * RES;
    float p = 0.f;
#pragma unroll 4
    for (int m = 0; m < RES / 32; ++m) {
        int j = gph * (RES / 32) + m;
        p += x[j] * Wout[(size_t)(1 + NF + j) * NR + r];
    }
    __shared__ float red[NTHR];
    red[tid] = p;
    __syncthreads();
    for (int s = NTHR / 2; s >= NR; s >>= 1) {
        if (tid < s) red[tid] += red[tid + s];
        __syncthreads();
    }
    if (tid < NR) {
        float y = Wout[tid];
#pragma unroll
        for (int f = 0; f < NF; ++f)
            y += inp[t * NF + f] * Wout[(1 + f) * NR + tid];
        Y[t * NR + tid] = y + red[tid];
    }
}

// ---------------------------------------------------------------------------
extern "C" void kernel_launch(void* const* d_in, const int* in_sizes, int n_in,
                              void* d_out, int out_size, void* d_ws, size_t ws_size,
                              hipStream_t stream) {
    const float* inp  = (const float*)d_in[0];   // (T, 8)
    const float* Win  = (const float*)d_in[1];   // (9, 2048)
    const float* W    = (const float*)d_in[2];   // (2048, 2048)
    const float* Wout = (const float*)d_in[3];   // (2057, 8)
    float* Y = (float*)d_out;                    // (T, 8)

    float* drive = (float*)d_ws;                            // 32 MB
    float* X     = drive + (size_t)T_STEPS * RES;           // 32 MB + 8 KB

    k_init<<<2048, NTHR, 0, stream>>>(X);
    k_drive<<<(T_STEPS * RES) / NTHR, NTHR, 0, stream>>>(inp, Win, drive);
    k_recur<<<K_WG, WTHR, 0, stream>>>(W, drive, X);
    k_readout<<<T_STEPS, NTHR, 0, stream>>>(inp, Wout, X, Y);
}